// Round 1
// baseline (51.552 us; speedup 1.0000x reference)
//
#include <hip/hip_runtime.h>
#include <math.h>

#define LMAX   6
#define NRAD   20
#define NELEM  4
#define NBATCH 2000
#define NPTS   100000
#define NLMTOT 49            // (LMAX+1)^2
#define FEAT   980           // NRAD * NLMTOT
#define OUTROW 3920          // NELEM * FEAT
#define CHUNK  64
#define ACT    245           // NLMTOT * 5 owner threads
#define PI_F   3.14159265358979323846f
#define RADK   0.44721359549995793f   // sqrt(2/RC), RC=10
#define INV_RC 0.1f

__global__ __launch_bounds__(256) void sfe_kernel(
    const float* __restrict__ coords,
    const int*   __restrict__ elem_ids,
    const int*   __restrict__ batch_ids,
    float*       __restrict__ out)
{
  const int b = blockIdx.x;
  const int t = threadIdx.x;

  __shared__ float sP[CHUNK][NLMTOT + NRAD + 1];  // 70-word stride (odd-ish, ok)
  __shared__ int   sElem[CHUNK];
  __shared__ float sC[NLMTOT];
  __shared__ int   sRange[2];

  // --- per-block init: normalization constants + segment range ---
  if (t < NLMTOT) {
    int lm = t;
    int l = 0;
    #pragma unroll
    for (int ll = 1; ll <= LMAX; ++ll) if (lm >= ll * ll) l = ll;
    int m  = lm - l * l - l;
    int am = m < 0 ? -m : m;
    float denom = 1.f;                 // (l+am)! / (l-am)!
    for (int k = l - am + 1; k <= l + am; ++k) denom *= (float)k;
    float nlm = sqrtf((float)(2 * l + 1) / denom);
    sC[lm] = (m == 0) ? nlm : 1.4142135623730951f * nlm;
  }
  if (t == 0) {
    int lo = 0, hi = NPTS;
    while (lo < hi) { int mid = (lo + hi) >> 1; if (batch_ids[mid] < b) lo = mid + 1; else hi = mid; }
    sRange[0] = lo;
    hi = NPTS;
    while (lo < hi) { int mid = (lo + hi) >> 1; if (batch_ids[mid] <= b) lo = mid + 1; else hi = mid; }
    sRange[1] = lo;
  }
  __syncthreads();
  const int start = sRange[0], end = sRange[1];

  // --- feature ownership: thread t -> (lm, n in {gn, gn+5, gn+10, gn+15}) ---
  const int te = (t < ACT) ? t : 0;
  const int lm = te % NLMTOT;
  const int gn = te / NLMTOT;          // 0..4
  int l = 0;
  #pragma unroll
  for (int ll = 1; ll <= LMAX; ++ll) if (lm >= ll * ll) l = ll;
  const int mi    = lm - l * l;
  const int nm    = 2 * l + 1;
  const int nv    = NRAD * nm;         // output stride per elem within l-block
  const int base4 = 4 * NRAD * l * l;  // NELEM * (feature offset of l-block)

  float acc[NELEM][4];
  #pragma unroll
  for (int e = 0; e < NELEM; ++e)
    #pragma unroll
    for (int k = 0; k < 4; ++k) acc[e][k] = 0.f;

  for (int c = start; c < end; c += CHUNK) {
    int cnt = end - c; if (cnt > CHUNK) cnt = CHUNK;

    // --- stage: one thread computes one point's Y[49] + rad[20] ---
    if (t < cnt) {
      int p = c + t;
      float x = coords[3 * p + 0], y = coords[3 * p + 1], z = coords[3 * p + 2];
      float r    = sqrtf(x * x + y * y + z * z);
      float invr = 1.f / r;
      x *= invr; y *= invr; z *= invr;

      float cs[LMAX + 1], sn[LMAX + 1];
      cs[0] = 1.f; sn[0] = 0.f;
      #pragma unroll
      for (int m = 1; m <= LMAX; ++m) {
        cs[m] = cs[m - 1] * x - sn[m - 1] * y;
        sn[m] = sn[m - 1] * x + cs[m - 1] * y;
      }
      float Q[LMAX + 1][LMAX + 1];
      Q[0][0] = 1.f;
      #pragma unroll
      for (int m = 1; m <= LMAX; ++m) Q[m][m] = -(float)(2 * m - 1) * Q[m - 1][m - 1];
      #pragma unroll
      for (int m = 0; m < LMAX; ++m) Q[m + 1][m] = (float)(2 * m + 1) * z * Q[m][m];
      #pragma unroll
      for (int m = 0; m <= LMAX; ++m) {
        #pragma unroll
        for (int ll = m + 2; ll <= LMAX; ++ll) {
          Q[ll][m] = ((float)(2 * ll - 1) * z * Q[ll - 1][m]
                    - (float)(ll + m - 1) * Q[ll - 2][m]) / (float)(ll - m);
        }
      }
      #pragma unroll
      for (int ll = 0; ll <= LMAX; ++ll) {
        #pragma unroll
        for (int m = -ll; m <= ll; ++m) {
          int am = m < 0 ? -m : m;
          float v = Q[ll][am] * sC[ll * ll + ll + m];
          if (m < 0)      v *= sn[am];
          else if (m > 0) v *= cs[am];
          sP[t][ll * ll + ll + m] = v;
        }
      }
      float a = PI_F * r * INV_RC;
      #pragma unroll
      for (int n = 1; n <= NRAD; ++n)
        sP[t][NLMTOT + n - 1] = RADK * sinf((float)n * a) * invr;
      sElem[t] = elem_ids[p];
    }
    __syncthreads();

    // --- accumulate: each owner thread, 4 features, branchless elem select ---
    if (t < ACT) {
      for (int p = 0; p < cnt; ++p) {
        int e = sElem[p];
        float yv = sP[p][lm];
        #pragma unroll
        for (int k = 0; k < 4; ++k) {
          float prod = yv * sP[p][NLMTOT + gn + 5 * k];
          #pragma unroll
          for (int ee = 0; ee < NELEM; ++ee)
            acc[ee][k] += (e == ee) ? prod : 0.f;
        }
      }
    }
    __syncthreads();
  }

  // --- write: out[b][NELEM*base_l + e*nv + n*nm + mi] ---
  if (t < ACT) {
    const long long obase = (long long)b * OUTROW + base4 + mi;
    #pragma unroll
    for (int e = 0; e < NELEM; ++e) {
      #pragma unroll
      for (int k = 0; k < 4; ++k) {
        int n = gn + 5 * k;
        out[obase + e * nv + (long long)n * nm] = acc[e][k];
      }
    }
  }
}

extern "C" void kernel_launch(void* const* d_in, const int* in_sizes, int n_in,
                              void* d_out, int out_size, void* d_ws, size_t ws_size,
                              hipStream_t stream) {
  const float* coords    = (const float*)d_in[0];
  const int*   elem_ids  = (const int*)d_in[1];
  const int*   batch_ids = (const int*)d_in[2];
  float*       out       = (float*)d_out;
  sfe_kernel<<<NBATCH, 256, 0, stream>>>(coords, elem_ids, batch_ids, out);
}

// Round 2
// 41.313 us; speedup vs baseline: 1.2479x; 1.2479x over previous
//
#include <hip/hip_runtime.h>
#include <math.h>

#define LMAX   6
#define NRAD   20
#define NELEM  4
#define NBATCH 2000
#define NPTS   100000
#define NLMTOT 49            // (LMAX+1)^2
#define FEAT   980           // NRAD * NLMTOT
#define OUTROW 3920          // NELEM * FEAT
#define CHUNK  64
#define ACT    245           // NLMTOT * 5 owner threads
#define SROW   71            // odd LDS stride -> conflict-free stage writes
#define PI_F   3.14159265358979323846f
#define RADK   0.44721359549995793f   // sqrt(2/RC), RC=10
#define INV_RC 0.1f

// --- pre-kernel: seg[b] = lower_bound(batch_ids, b), b in [0, NBATCH] ---
__global__ __launch_bounds__(256) void seg_kernel(
    const int* __restrict__ batch_ids, int* __restrict__ seg)
{
  int b = blockIdx.x * blockDim.x + threadIdx.x;
  if (b > NBATCH) return;
  int lo = 0, hi = NPTS;
  while (lo < hi) { int mid = (lo + hi) >> 1; if (batch_ids[mid] < b) lo = mid + 1; else hi = mid; }
  seg[b] = lo;
}

// --- main: one block per (batch, elem) ---
__global__ __launch_bounds__(256) void sfe_kernel(
    const float* __restrict__ coords,
    const int*   __restrict__ elem_ids,
    const int*   __restrict__ seg,
    float*       __restrict__ out)
{
  const int b = blockIdx.x >> 2;       // 4 consecutive blocks share a batch (L2 locality)
  const int e = blockIdx.x & 3;
  const int t = threadIdx.x;

  __shared__ float sP[CHUNK][SROW];    // [point][0:49 Y, 49:69 rad]
  __shared__ int   sIdx[CHUNK];
  __shared__ float sC[NLMTOT];
  __shared__ int   sMcnt;

  // normalization constants
  if (t < NLMTOT) {
    int lm = t, l = 0;
    #pragma unroll
    for (int ll = 1; ll <= LMAX; ++ll) if (lm >= ll * ll) l = ll;
    int m  = lm - l * l - l;
    int am = m < 0 ? -m : m;
    float denom = 1.f;                 // (l+am)! / (l-am)!
    for (int k = l - am + 1; k <= l + am; ++k) denom *= (float)k;
    float nlm = sqrtf((float)(2 * l + 1) / denom);
    sC[lm] = (m == 0) ? nlm : 1.4142135623730951f * nlm;
  }

  const int start = seg[b], end = seg[b + 1];

  // feature ownership: thread t -> (lm, n in {gn, gn+5, gn+10, gn+15})
  const int te = (t < ACT) ? t : 0;
  const int lm = te % NLMTOT;
  const int gn = te / NLMTOT;          // 0..4
  int l = 0;
  #pragma unroll
  for (int ll = 1; ll <= LMAX; ++ll) if (lm >= ll * ll) l = ll;
  const int mi    = lm - l * l;
  const int nm    = 2 * l + 1;
  const int nv    = NRAD * nm;         // per-elem stride inside l-block
  const int base4 = 4 * NRAD * l * l;  // NELEM * (feature offset of l-block)

  float acc[4] = {0.f, 0.f, 0.f, 0.f};

  __syncthreads();   // sC ready

  for (int c = start; c < end; c += CHUNK) {
    int cnt = end - c; if (cnt > CHUNK) cnt = CHUNK;

    // --- compact matching points (wave 0 only) ---
    if (t < 64) {
      bool match = (t < cnt) && (elem_ids[c + t] == e);
      unsigned long long mask = __ballot(match);
      int slot = __popcll(mask & ((1ULL << t) - 1ULL));
      if (match) sIdx[slot] = c + t;
      if (t == 0) sMcnt = __popcll(mask);
    }
    __syncthreads();
    const int mcnt = sMcnt;

    // --- stage: one thread per matching point: Y[49] + rad[20] ---
    if (t < mcnt) {
      int p = sIdx[t];
      float x = coords[3 * p + 0], y = coords[3 * p + 1], z = coords[3 * p + 2];
      float r    = sqrtf(x * x + y * y + z * z);
      float invr = 1.f / r;
      x *= invr; y *= invr; z *= invr;

      float cs[LMAX + 1], sn[LMAX + 1];
      cs[0] = 1.f; sn[0] = 0.f;
      #pragma unroll
      for (int m = 1; m <= LMAX; ++m) {
        cs[m] = cs[m - 1] * x - sn[m - 1] * y;
        sn[m] = sn[m - 1] * x + cs[m - 1] * y;
      }
      float Q[LMAX + 1][LMAX + 1];
      Q[0][0] = 1.f;
      #pragma unroll
      for (int m = 1; m <= LMAX; ++m) Q[m][m] = -(float)(2 * m - 1) * Q[m - 1][m - 1];
      #pragma unroll
      for (int m = 0; m < LMAX; ++m) Q[m + 1][m] = (float)(2 * m + 1) * z * Q[m][m];
      #pragma unroll
      for (int m = 0; m <= LMAX; ++m) {
        #pragma unroll
        for (int ll = m + 2; ll <= LMAX; ++ll) {
          Q[ll][m] = ((float)(2 * ll - 1) * z * Q[ll - 1][m]
                    - (float)(ll + m - 1) * Q[ll - 2][m]) / (float)(ll - m);
        }
      }
      #pragma unroll
      for (int ll = 0; ll <= LMAX; ++ll) {
        #pragma unroll
        for (int m = -ll; m <= ll; ++m) {
          int am = m < 0 ? -m : m;
          float v = Q[ll][am] * sC[ll * ll + ll + m];
          if (m < 0)      v *= sn[am];
          else if (m > 0) v *= cs[am];
          sP[t][ll * ll + ll + m] = v;
        }
      }
      // radial: sin(n*a) by Chebyshev recurrence, one sincos total
      float a = PI_F * r * INV_RC;
      float s1, c1;
      __sincosf(a, &s1, &c1);
      float twoc = 2.f * c1;
      float sprev = 0.f, scur = s1;
      float scale = RADK * invr;
      #pragma unroll
      for (int n = 1; n <= NRAD; ++n) {
        sP[t][NLMTOT + n - 1] = scale * scur;
        float snext = twoc * scur - sprev;
        sprev = scur; scur = snext;
      }
    }
    __syncthreads();

    // --- accumulate: 245 owner threads, 4 features each, no predication ---
    if (t < ACT) {
      for (int p = 0; p < mcnt; ++p) {
        float yv = sP[p][lm];
        #pragma unroll
        for (int k = 0; k < 4; ++k)
          acc[k] += yv * sP[p][NLMTOT + gn + 5 * k];
      }
    }
    __syncthreads();
  }

  // --- write: out[b][base4 + e*nv + n*nm + mi] ---
  if (t < ACT) {
    const long long obase = (long long)b * OUTROW + base4 + (long long)e * nv + mi;
    #pragma unroll
    for (int k = 0; k < 4; ++k) {
      int n = gn + 5 * k;
      out[obase + (long long)n * nm] = acc[k];
    }
  }
}

extern "C" void kernel_launch(void* const* d_in, const int* in_sizes, int n_in,
                              void* d_out, int out_size, void* d_ws, size_t ws_size,
                              hipStream_t stream) {
  const float* coords    = (const float*)d_in[0];
  const int*   elem_ids  = (const int*)d_in[1];
  const int*   batch_ids = (const int*)d_in[2];
  float*       out       = (float*)d_out;
  int*         seg       = (int*)d_ws;   // NBATCH+1 ints

  seg_kernel<<<(NBATCH + 1 + 255) / 256, 256, 0, stream>>>(batch_ids, seg);
  sfe_kernel<<<NBATCH * NELEM, 256, 0, stream>>>(coords, elem_ids, seg, out);
}